// Round 1
// baseline (366.203 us; speedup 1.0000x reference)
//
#include <hip/hip_runtime.h>
#include <math.h>

#define B 256
#define F 32
#define L 4096
#define LOG2L 12
#define NT 256          // threads per block (4 waves)
#define NBF (L / 2)     // butterflies per stage

#define TWO_PI 6.28318530717958647692f

__device__ __forceinline__ int brev12(int i) {
    return (int)(__brev((unsigned)i) >> 20);
}

// Build twiddle table tw[k] = exp(sign * i * 2*pi * k / L), k in [0, L/2)
__device__ __forceinline__ void build_tw(float2* tw, float sign, int tid) {
    const float c = sign * TWO_PI / (float)L;
    for (int k = tid; k < L / 2; k += NT) {
        float sv, cv;
        sincosf(c * (float)k, &sv, &cv);
        tw[k] = make_float2(cv, sv);
    }
}

// In-place radix-2 DIT FFT over data[0..L). Input must already be in
// bit-reversed order. Caller must __syncthreads() after loading data/tw.
// tw has the sign baked in (-1 fwd / +1 inv).
__device__ __forceinline__ void fft_lds(float2* data, const float2* tw, int tid) {
    #pragma unroll
    for (int s = 1; s <= LOG2L; ++s) {
        const int half = 1 << (s - 1);
        const int tsh  = LOG2L - s;          // twiddle index stride shift
        for (int t = tid; t < NBF; t += NT) {
            const int pos = t & (half - 1);
            const int i0  = (t << 1) - pos;  // == (t/half)*2*half + pos
            const int i1  = i0 + half;
            const float2 w = tw[pos << tsh];
            const float2 a = data[i0];
            const float2 b = data[i1];
            const float br = b.x * w.x - b.y * w.y;
            const float bi = b.x * w.y + b.y * w.x;
            data[i0] = make_float2(a.x + br, a.y + bi);
            data[i1] = make_float2(a.x - br, a.y - bi);
        }
        __syncthreads();
    }
}

// Kernel 1: per filter f — softmax(window row), atoms = w * exp(-2pi i fr n),
// forward FFT, store G[f,k] = conj(Af[f,k]).  32 blocks, perf-irrelevant.
__global__ void __launch_bounds__(NT) atoms_kernel(const float* __restrict__ wp,
                                                   const float* __restrict__ fp,
                                                   float2* __restrict__ G) {
    __shared__ float2 data[L];
    __shared__ float2 tw[L / 2];
    __shared__ float red[NT / 64];
    const int f = blockIdx.x;
    const int tid = threadIdx.x;
    const float* row = wp + (size_t)f * L;

    // --- max reduce over the 4096-length row ---
    float m = -INFINITY;
    for (int i = tid; i < L; i += NT) m = fmaxf(m, row[i]);
    #pragma unroll
    for (int off = 32; off; off >>= 1) m = fmaxf(m, __shfl_down(m, off));
    if ((tid & 63) == 0) red[tid >> 6] = m;
    __syncthreads();
    if (tid == 0) {
        float mm = red[0];
        for (int w = 1; w < NT / 64; ++w) mm = fmaxf(mm, red[w]);
        red[0] = mm;
    }
    __syncthreads();
    m = red[0];
    __syncthreads();   // red reused below

    // --- sum of exp ---
    float sum = 0.0f;
    for (int i = tid; i < L; i += NT) sum += expf(row[i] - m);
    #pragma unroll
    for (int off = 32; off; off >>= 1) sum += __shfl_down(sum, off);
    if ((tid & 63) == 0) red[tid >> 6] = sum;
    __syncthreads();
    if (tid == 0) {
        float ss = 0.0f;
        for (int w = 0; w < NT / 64; ++w) ss += red[w];
        red[0] = ss;
    }
    __syncthreads();
    sum = red[0];

    const float inv = 1.0f / sum;
    // fr = 0.5 * sigmoid(fp[f])
    const float fr = 0.5f / (1.0f + expf(-fp[f]));
    const float w0 = -TWO_PI * fr;

    // atoms into LDS, bit-reversed for DIT
    for (int i = tid; i < L; i += NT) {
        const float e = expf(row[i] - m) * inv;
        float sv, cv;
        sincosf(w0 * (float)i, &sv, &cv);
        data[brev12(i)] = make_float2(e * cv, e * sv);
    }
    build_tw(tw, -1.0f, tid);
    __syncthreads();
    fft_lds(data, tw, tid);

    float2* g = G + (size_t)f * L;
    for (int k = tid; k < L; k += NT) {
        const float2 v = data[k];
        g[k] = make_float2(v.x, -v.y);   // store conj(Af)
    }
}

// Kernel 2: forward FFT of each x row.  256 blocks.
__global__ void __launch_bounds__(NT) fftx_kernel(const float* __restrict__ x,
                                                  float2* __restrict__ Xf) {
    __shared__ float2 data[L];
    __shared__ float2 tw[L / 2];
    const int b = blockIdx.x;
    const int tid = threadIdx.x;
    const float* row = x + (size_t)b * L;

    for (int i = tid; i < L; i += NT)
        data[brev12(i)] = make_float2(row[i], 0.0f);
    build_tw(tw, -1.0f, tid);
    __syncthreads();
    fft_lds(data, tw, tid);

    float2* o = Xf + (size_t)b * L;
    for (int k = tid; k < L; k += NT) o[k] = data[k];
}

// Kernel 3: per (b,f) — P = Xf[b] * G[f], inverse FFT, write Re/L.
// 8192 blocks; this is the hot kernel.
__global__ void __launch_bounds__(NT) corr_kernel(const float2* __restrict__ Xf,
                                                  const float2* __restrict__ G,
                                                  float* __restrict__ out) {
    __shared__ float2 data[L];
    __shared__ float2 tw[L / 2];
    const int blk = blockIdx.x;
    const int b = blk >> 5;        // / F
    const int f = blk & (F - 1);   // % F
    const int tid = threadIdx.x;
    const float2* xr = Xf + (size_t)b * L;
    const float2* gr = G + (size_t)f * L;

    for (int k = tid; k < L; k += NT) {
        const float2 X = xr[k];
        const float2 Gk = gr[k];
        data[brev12(k)] = make_float2(X.x * Gk.x - X.y * Gk.y,
                                      X.x * Gk.y + X.y * Gk.x);
    }
    build_tw(tw, 1.0f, tid);
    __syncthreads();
    fft_lds(data, tw, tid);

    float* o = out + (size_t)blk * L;   // blk == b*F + f, matches [B,F,L]
    const float s = 1.0f / (float)L;
    for (int t = tid; t < L; t += NT) o[t] = data[t].x * s;
}

extern "C" void kernel_launch(void* const* d_in, const int* in_sizes, int n_in,
                              void* d_out, int out_size, void* d_ws, size_t ws_size,
                              hipStream_t stream) {
    (void)in_sizes; (void)n_in; (void)out_size; (void)ws_size;
    const float* x  = (const float*)d_in[0];   // [B, L]
    const float* wp = (const float*)d_in[1];   // [F, L]
    const float* fp = (const float*)d_in[2];   // [1, F]
    float* out = (float*)d_out;                // [B, F, L]

    float2* Xf = (float2*)d_ws;                // B*L complex = 8 MB
    float2* G  = Xf + (size_t)B * L;           // F*L complex = 1 MB

    atoms_kernel<<<dim3(F), dim3(NT), 0, stream>>>(wp, fp, G);
    fftx_kernel<<<dim3(B), dim3(NT), 0, stream>>>(x, Xf);
    corr_kernel<<<dim3(B * F), dim3(NT), 0, stream>>>(Xf, G, out);
}

// Round 2
// 203.305 us; speedup vs baseline: 1.8013x; 1.8013x over previous
//
#include <hip/hip_runtime.h>
#include <math.h>

#define B 256
#define F 32
#define L 4096
#define NT 256
#define TWO_PI 6.28318530717958647692f

// LDS padding: +1 float2 per 16 -> even bank-pair spread for all FFT stage strides
__device__ __forceinline__ int pidx(int i) { return i + (i >> 4); }

// reverse the 3 base-16 digits of i in [0,4096)
__device__ __forceinline__ int rev3(int i) {
    return ((i & 15) << 8) | (i & 0xF0) | (i >> 8);
}

__device__ __forceinline__ float2 cmul(float2 a, float2 b) {
    return make_float2(a.x * b.x - a.y * b.y, a.x * b.y + a.y * b.x);
}
__device__ __forceinline__ float2 cmulc(float2 a, float cr, float ci) {
    return make_float2(a.x * cr - a.y * ci, a.x * ci + a.y * cr);
}

// radix-4 butterfly, SGN=-1 forward, +1 inverse
template<int SGN>
__device__ __forceinline__ void dft4(float2& a, float2& b, float2& c, float2& d) {
    const float s = (float)SGN;
    float2 t0 = make_float2(a.x + c.x, a.y + c.y);
    float2 t1 = make_float2(a.x - c.x, a.y - c.y);
    float2 t2 = make_float2(b.x + d.x, b.y + d.y);
    float2 t3 = make_float2(b.x - d.x, b.y - d.y);
    float2 it3 = make_float2(-s * t3.y, s * t3.x);   // SGN*i*t3
    a = make_float2(t0.x + t2.x, t0.y + t2.y);
    c = make_float2(t0.x - t2.x, t0.y - t2.y);
    b = make_float2(t1.x + it3.x, t1.y + it3.y);
    d = make_float2(t1.x - it3.x, t1.y - it3.y);
}

// 16-point DFT in registers: v[p] = sum_q v_in[q] * exp(SGN*2pi*i*p*q/16)
template<int SGN>
__device__ __forceinline__ void dft16(float2 v[16]) {
    const float s = (float)SGN;
    const float C1 = 0.92387953251128675613f;   // cos(pi/8)
    const float S1 = 0.38268343236508977173f;   // sin(pi/8)
    const float C2 = 0.70710678118654752440f;   // cos(pi/4)
    #pragma unroll
    for (int c = 0; c < 4; ++c) dft4<SGN>(v[c], v[c + 4], v[c + 8], v[c + 12]);
    // twiddles W16^{m*c} applied to slot c+4m
    v[5]  = cmulc(v[5],  C1,  s * S1);              // W^1
    v[6]  = cmulc(v[6],  C2,  s * C2);              // W^2
    v[7]  = cmulc(v[7],  S1,  s * C1);              // W^3
    v[9]  = cmulc(v[9],  C2,  s * C2);              // W^2
    v[10] = make_float2(-s * v[10].y, s * v[10].x); // W^4 = SGN*i
    v[11] = cmulc(v[11], -C2, s * C2);              // W^6
    v[13] = cmulc(v[13], S1,  s * C1);              // W^3
    v[14] = cmulc(v[14], -C2, s * C2);              // W^6
    v[15] = cmulc(v[15], -C1, -s * S1);             // W^9
    float2 o[16];
    #pragma unroll
    for (int m = 0; m < 4; ++m) {
        float2 a = v[4*m], b = v[4*m+1], c = v[4*m+2], d = v[4*m+3];
        dft4<SGN>(a, b, c, d);
        o[m] = a; o[m+4] = b; o[m+8] = c; o[m+12] = d;
    }
    #pragma unroll
    for (int i = 0; i < 16; ++i) v[i] = o[i];
}

// v[q] *= w1^q for q=1..15 (recursive powers; ~1e-6 rel err, fine vs 1e-3 tol)
__device__ __forceinline__ void twiddle_pow(float2 v[16], float2 w1) {
    float2 w = w1;
    #pragma unroll
    for (int q = 1; q < 16; ++q) {
        v[q] = cmul(v[q], w);
        w = cmul(w, w1);
    }
}

// twp[pidx(m)] = exp(sgn*2pi*i*m/L), m in [0,256)
__device__ __forceinline__ void build_twid(float2* twp, float sgn, int tid) {
    float ang = sgn * (TWO_PI / (float)L) * (float)tid;
    float sv, cv;
    sincosf(ang, &sv, &cv);
    twp[pidx(tid)] = make_float2(cv, sv);
}

// ---------------- Kernel 1: atoms + Hermitian pairing (F/2 = 16 blocks) ------
// For filter pair (2j, 2j+1): softmax window, atom, forward DIF FFT (scrambled),
// unscramble to natural, build C_j(k) = (G2j(k) + i*G2j1(k))/L with
// G_f(k) = (conj(Af(k)) + Af(L-k))/2, store scrambled: Cs[j][i] = C_j(rev3(i)).
__global__ void __launch_bounds__(NT) atoms_kernel(const float* __restrict__ wp,
                                                   const float* __restrict__ fp,
                                                   float2* __restrict__ Cs) {
    __shared__ float2 lds[L + (L >> 4)];
    __shared__ float2 twp[272];
    __shared__ float2 bufa[L];
    __shared__ float2 bufb[L];
    __shared__ float red[4];
    const int j = blockIdx.x;
    const int t = threadIdx.x;
    build_twid(twp, -1.0f, t);

    for (int half = 0; half < 2; ++half) {
        const int f = 2 * j + half;
        const float* row = wp + (size_t)f * L;
        // softmax max
        float m = -INFINITY;
        for (int i = t; i < L; i += NT) m = fmaxf(m, row[i]);
        #pragma unroll
        for (int off = 32; off; off >>= 1) m = fmaxf(m, __shfl_down(m, off));
        if ((t & 63) == 0) red[t >> 6] = m;
        __syncthreads();
        m = fmaxf(fmaxf(red[0], red[1]), fmaxf(red[2], red[3]));
        __syncthreads();
        // softmax sum
        float sum = 0.0f;
        for (int i = t; i < L; i += NT) sum += expf(row[i] - m);
        #pragma unroll
        for (int off = 32; off; off >>= 1) sum += __shfl_down(sum, off);
        if ((t & 63) == 0) red[t >> 6] = sum;
        __syncthreads();
        sum = red[0] + red[1] + red[2] + red[3];
        __syncthreads();   // red reused next half
        const float inv = 1.0f / sum;
        const float fr = 0.5f / (1.0f + expf(-fp[f]));
        const float w0 = -TWO_PI * fr;
        // atom values, natural order into LDS
        #pragma unroll
        for (int c = 0; c < 16; ++c) {
            int n = t + 256 * c;
            float e = expf(row[n] - m) * inv;
            float sv, cv;
            sincosf(w0 * (float)n, &sv, &cv);
            lds[pidx(n)] = make_float2(e * cv, e * sv);
        }
        __syncthreads();
        float2 v[16];
        // DIF stage A (M=4096)
        #pragma unroll
        for (int q = 0; q < 16; ++q) v[q] = lds[pidx(t + 256 * q)];
        dft16<-1>(v);
        twiddle_pow(v, twp[pidx(t)]);
        #pragma unroll
        for (int p = 0; p < 16; ++p) lds[pidx(t + 256 * p)] = v[p];
        __syncthreads();
        // DIF stage B (M=256)
        {
            const int base = (t >> 4) * 256 + (t & 15);
            #pragma unroll
            for (int q = 0; q < 16; ++q) v[q] = lds[pidx(base + 16 * q)];
            dft16<-1>(v);
            twiddle_pow(v, twp[pidx(16 * (t & 15))]);
            #pragma unroll
            for (int p = 0; p < 16; ++p) lds[pidx(base + 16 * p)] = v[p];
        }
        __syncthreads();
        // DIF stage C (M=16) + unscramble straight into natural-order buffer
        #pragma unroll
        for (int q = 0; q < 16; ++q) v[q] = lds[pidx(16 * t + q)];
        dft16<-1>(v);
        float2* buf = half ? bufb : bufa;
        #pragma unroll
        for (int r = 0; r < 16; ++r) buf[rev3(16 * t + r)] = v[r];
        __syncthreads();
    }
    // pairing + scramble + scale, coalesced global writes
    const float sc = 0.5f / (float)L;
    float2* co = Cs + (size_t)j * L;
    #pragma unroll
    for (int c = 0; c < 16; ++c) {
        int i = t + 256 * c;
        int k = rev3(i);
        int km = (L - k) & (L - 1);
        float2 a0k = bufa[k], a0m = bufa[km];
        float2 a1k = bufb[k], a1m = bufb[km];
        float g0r = a0k.x + a0m.x, g0i = a0m.y - a0k.y;   // 2*G_{2j}(k)
        float g1r = a1k.x + a1m.x, g1i = a1m.y - a1k.y;   // 2*G_{2j+1}(k)
        co[i] = make_float2((g0r - g1i) * sc, (g0i + g1r) * sc);
    }
}

// ---------------- Kernel 2: forward DIF FFT of x rows (B = 256 blocks) -------
// Xs[b][i] = X_b(rev3(i))
__global__ void __launch_bounds__(NT) fftx_kernel(const float* __restrict__ x,
                                                  float2* __restrict__ Xs) {
    __shared__ float2 lds[L + (L >> 4)];
    __shared__ float2 twp[272];
    const int bb = blockIdx.x;
    const int t = threadIdx.x;
    build_twid(twp, -1.0f, t);
    const float* row = x + (size_t)bb * L;
    float2 v[16];
    // stage A directly from global (coalesced: lane-consecutive addresses)
    #pragma unroll
    for (int q = 0; q < 16; ++q) v[q] = make_float2(row[t + 256 * q], 0.0f);
    dft16<-1>(v);
    twiddle_pow(v, twp[pidx(t)]);
    #pragma unroll
    for (int p = 0; p < 16; ++p) lds[pidx(t + 256 * p)] = v[p];
    __syncthreads();
    // stage B
    {
        const int base = (t >> 4) * 256 + (t & 15);
        #pragma unroll
        for (int q = 0; q < 16; ++q) v[q] = lds[pidx(base + 16 * q)];
        dft16<-1>(v);
        twiddle_pow(v, twp[pidx(16 * (t & 15))]);
        #pragma unroll
        for (int p = 0; p < 16; ++p) lds[pidx(base + 16 * p)] = v[p];
    }
    __syncthreads();
    // stage C, write scrambled spectrum straight to global (vectorized)
    #pragma unroll
    for (int q = 0; q < 16; ++q) v[q] = lds[pidx(16 * t + q)];
    dft16<-1>(v);
    float4* o4 = (float4*)(Xs + (size_t)bb * L + 16 * t);
    #pragma unroll
    for (int h = 0; h < 8; ++h)
        o4[h] = make_float4(v[2*h].x, v[2*h].y, v[2*h+1].x, v[2*h+1].y);
}

// ---------------- Kernel 3: product + inverse DIT FFT (B*F/2 = 4096 blocks) --
// Natural-order real outputs for filters 2j (Re) and 2j+1 (Im).
__global__ void __launch_bounds__(NT) corr_kernel(const float2* __restrict__ Xs,
                                                  const float2* __restrict__ Cs,
                                                  float* __restrict__ out) {
    __shared__ float2 lds[L + (L >> 4)];
    __shared__ float2 twp[272];
    const int blk = blockIdx.x;
    const int b = blk >> 4;
    const int jf = blk & 15;
    const int t = threadIdx.x;
    build_twid(twp, 1.0f, t);

    const float2* xr = Xs + (size_t)b * L;
    const float2* cr = Cs + (size_t)jf * L;

    // DIT stage 0 (M=16): product from global, dft16, no twiddle
    float2 v[16];
    const float4* x4 = (const float4*)(xr + 16 * t);
    const float4* c4 = (const float4*)(cr + 16 * t);
    #pragma unroll
    for (int h = 0; h < 8; ++h) {
        float4 xa = x4[h];
        float4 ca = c4[h];
        v[2*h]   = cmul(make_float2(xa.x, xa.y), make_float2(ca.x, ca.y));
        v[2*h+1] = cmul(make_float2(xa.z, xa.w), make_float2(ca.z, ca.w));
    }
    dft16<1>(v);
    #pragma unroll
    for (int r = 0; r < 16; ++r) lds[pidx(16 * t + r)] = v[r];
    __syncthreads();
    // DIT stage 1 (M=256): twiddle then dft, in-place on own slots
    {
        const int base = (t >> 4) * 256 + (t & 15);
        #pragma unroll
        for (int q = 0; q < 16; ++q) v[q] = lds[pidx(base + 16 * q)];
        twiddle_pow(v, twp[pidx(16 * (t & 15))]);
        dft16<1>(v);
        #pragma unroll
        for (int r = 0; r < 16; ++r) lds[pidx(base + 16 * r)] = v[r];
    }
    __syncthreads();
    // DIT stage 2 (M=4096): outputs straight to global, natural order
    {
        #pragma unroll
        for (int q = 0; q < 16; ++q) v[q] = lds[pidx(t + 256 * q)];
        twiddle_pow(v, twp[pidx(t)]);
        dft16<1>(v);
        float* o0 = out + ((size_t)b * F + 2 * jf) * L;
        float* o1 = o0 + L;
        #pragma unroll
        for (int r = 0; r < 16; ++r) {
            __builtin_nontemporal_store(v[r].x, o0 + t + 256 * r);
            __builtin_nontemporal_store(v[r].y, o1 + t + 256 * r);
        }
    }
}

extern "C" void kernel_launch(void* const* d_in, const int* in_sizes, int n_in,
                              void* d_out, int out_size, void* d_ws, size_t ws_size,
                              hipStream_t stream) {
    (void)in_sizes; (void)n_in; (void)out_size; (void)ws_size;
    const float* x  = (const float*)d_in[0];   // [B, L]
    const float* wp = (const float*)d_in[1];   // [F, L]
    const float* fp = (const float*)d_in[2];   // [1, F]
    float* out = (float*)d_out;                // [B, F, L]

    float2* Xs = (float2*)d_ws;                // B*L complex, scrambled spectra
    float2* Cs = Xs + (size_t)B * L;           // (F/2)*L complex, paired filters

    atoms_kernel<<<dim3(F / 2), dim3(NT), 0, stream>>>(wp, fp, Cs);
    fftx_kernel<<<dim3(B), dim3(NT), 0, stream>>>(x, Xs);
    corr_kernel<<<dim3(B * F / 2), dim3(NT), 0, stream>>>(Xs, Cs, out);
}

// Round 3
// 186.288 us; speedup vs baseline: 1.9658x; 1.0913x over previous
//
#include <hip/hip_runtime.h>
#include <math.h>

#define B 256
#define F 32
#define L 4096
#define NT 256
#define TWO_PI 6.28318530717958647692f

// LDS padding: +1 float2 per 16 -> conflict-free for all FFT stage strides
__device__ __forceinline__ int pidx(int i) { return i + (i >> 4); }

// reverse the 3 base-16 digits of i in [0,4096)
__device__ __forceinline__ int rev3(int i) {
    return ((i & 15) << 8) | (i & 0xF0) | (i >> 8);
}

__device__ __forceinline__ float2 cmul(float2 a, float2 b) {
    return make_float2(a.x * b.x - a.y * b.y, a.x * b.y + a.y * b.x);
}
__device__ __forceinline__ float2 cmulc(float2 a, float cr, float ci) {
    return make_float2(a.x * cr - a.y * ci, a.x * ci + a.y * cr);
}

// radix-4 butterfly, SGN=-1 forward, +1 inverse
template<int SGN>
__device__ __forceinline__ void dft4(float2& a, float2& b, float2& c, float2& d) {
    const float s = (float)SGN;
    float2 t0 = make_float2(a.x + c.x, a.y + c.y);
    float2 t1 = make_float2(a.x - c.x, a.y - c.y);
    float2 t2 = make_float2(b.x + d.x, b.y + d.y);
    float2 t3 = make_float2(b.x - d.x, b.y - d.y);
    float2 it3 = make_float2(-s * t3.y, s * t3.x);   // SGN*i*t3
    a = make_float2(t0.x + t2.x, t0.y + t2.y);
    c = make_float2(t0.x - t2.x, t0.y - t2.y);
    b = make_float2(t1.x + it3.x, t1.y + it3.y);
    d = make_float2(t1.x - it3.x, t1.y - it3.y);
}

// 16-point DFT in registers: v[p] = sum_q v_in[q] * exp(SGN*2pi*i*p*q/16)
template<int SGN>
__device__ __forceinline__ void dft16(float2 v[16]) {
    const float s = (float)SGN;
    const float C1 = 0.92387953251128675613f;   // cos(pi/8)
    const float S1 = 0.38268343236508977173f;   // sin(pi/8)
    const float C2 = 0.70710678118654752440f;   // cos(pi/4)
    #pragma unroll
    for (int c = 0; c < 4; ++c) dft4<SGN>(v[c], v[c + 4], v[c + 8], v[c + 12]);
    v[5]  = cmulc(v[5],  C1,  s * S1);              // W^1
    v[6]  = cmulc(v[6],  C2,  s * C2);              // W^2
    v[7]  = cmulc(v[7],  S1,  s * C1);              // W^3
    v[9]  = cmulc(v[9],  C2,  s * C2);              // W^2
    v[10] = make_float2(-s * v[10].y, s * v[10].x); // W^4 = SGN*i
    v[11] = cmulc(v[11], -C2, s * C2);              // W^6
    v[13] = cmulc(v[13], S1,  s * C1);              // W^3
    v[14] = cmulc(v[14], -C2, s * C2);              // W^6
    v[15] = cmulc(v[15], -C1, -s * S1);             // W^9
    float2 o[16];
    #pragma unroll
    for (int m = 0; m < 4; ++m) {
        float2 a = v[4*m], b = v[4*m+1], c = v[4*m+2], d = v[4*m+3];
        dft4<SGN>(a, b, c, d);
        o[m] = a; o[m+4] = b; o[m+8] = c; o[m+12] = d;
    }
    #pragma unroll
    for (int i = 0; i < 16; ++i) v[i] = o[i];
}

// v[q] *= w1^q for q=1..15 (recursive powers)
__device__ __forceinline__ void twiddle_pow(float2 v[16], float2 w1) {
    float2 w = w1;
    #pragma unroll
    for (int q = 1; q < 16; ++q) {
        v[q] = cmul(v[q], w);
        w = cmul(w, w1);
    }
}

// twp[pidx(t)] = exp(SGN*i*2pi*t/L), t in [0,256)
// T1[17*(t>>4)+(t&15)] = exp(SGN*i*2pi*(t>>4)*(t&15)/256)   (stage-"256" twiddles)
template<int SGN>
__device__ __forceinline__ void build_tables(float2* twp, float2* T1, int t) {
    float sv, cv;
    float a1 = (float)SGN * (TWO_PI / (float)L) * (float)t;
    sincosf(a1, &sv, &cv);
    twp[pidx(t)] = make_float2(cv, sv);
    float a2 = (float)SGN * (TWO_PI / 256.0f) * (float)((t >> 4) * (t & 15));
    sincosf(a2, &sv, &cv);
    T1[17 * (t >> 4) + (t & 15)] = make_float2(cv, sv);
}

// Forward DIF FFT: input v[q] = data[t + 256*q] (natural order).
// Output: v[r] = X(rev3(16*t + r))  (digit-reversed / scrambled).
// Caller must __syncthreads() after build_tables and before calling.
__device__ __forceinline__ void fft_dif_fwd(float2 v[16], float2* lds,
                                            const float2* twp, const float2* T1, int t) {
    // stage A (span 4096)
    dft16<-1>(v);
    twiddle_pow(v, twp[pidx(t)]);
    #pragma unroll
    for (int p = 0; p < 16; ++p) lds[pidx(t + 256 * p)] = v[p];
    __syncthreads();
    // stage B (span 256): twiddles from T1 table (4-way broadcast reads)
    const int base = (t >> 4) * 256 + (t & 15);
    #pragma unroll
    for (int q = 0; q < 16; ++q) v[q] = lds[pidx(base + 16 * q)];
    dft16<-1>(v);
    {
        const float2* Tr = T1 + 17 * (t & 15);
        #pragma unroll
        for (int p = 1; p < 16; ++p) v[p] = cmul(v[p], Tr[p]);
    }
    #pragma unroll
    for (int p = 0; p < 16; ++p) lds[pidx(base + 16 * p)] = v[p];
    __syncthreads();
    // stage C (span 16)
    #pragma unroll
    for (int q = 0; q < 16; ++q) v[q] = lds[pidx(16 * t + q)];
    dft16<-1>(v);
}

// ---------------- Kernel 1: fused prep (F + B = 288 blocks) ------------------
// Blocks [0,F): per-filter softmax + atom + forward FFT -> Anat[f] (natural).
// Blocks [F,F+B): forward FFT of x rows -> Xs[b] (scrambled, contiguous).
// Atom blocks first so they start immediately (they're the long pole).
__global__ void __launch_bounds__(NT) prep_kernel(const float* __restrict__ x,
                                                  const float* __restrict__ wp,
                                                  const float* __restrict__ fp,
                                                  float2* __restrict__ Xs,
                                                  float2* __restrict__ Anat) {
    __shared__ float2 lds[L + (L >> 4)];
    __shared__ float2 twp[272];
    __shared__ float2 T1[272];
    __shared__ float red[4];
    const int t = threadIdx.x;
    build_tables<-1>(twp, T1, t);
    float2 v[16];

    if (blockIdx.x < F) {
        const int f = blockIdx.x;
        const float* row = wp + (size_t)f * L;
        // register-resident softmax (single global pass)
        float rv[16];
        #pragma unroll
        for (int c = 0; c < 16; ++c) rv[c] = row[t + 256 * c];
        float m = -INFINITY;
        #pragma unroll
        for (int c = 0; c < 16; ++c) m = fmaxf(m, rv[c]);
        #pragma unroll
        for (int off = 32; off; off >>= 1) m = fmaxf(m, __shfl_down(m, off));
        if ((t & 63) == 0) red[t >> 6] = m;
        __syncthreads();
        m = fmaxf(fmaxf(red[0], red[1]), fmaxf(red[2], red[3]));
        __syncthreads();
        float s = 0.0f;
        #pragma unroll
        for (int c = 0; c < 16; ++c) { rv[c] = expf(rv[c] - m); s += rv[c]; }
        #pragma unroll
        for (int off = 32; off; off >>= 1) s += __shfl_down(s, off);
        if ((t & 63) == 0) red[t >> 6] = s;
        __syncthreads();
        s = red[0] + red[1] + red[2] + red[3];
        const float inv = 1.0f / s;
        const float fr = 0.5f / (1.0f + expf(-fp[f]));
        const float w0 = -TWO_PI * fr;
        #pragma unroll
        for (int c = 0; c < 16; ++c) {
            const int n = t + 256 * c;
            const float e = rv[c] * inv;
            float sv, cv;
            sincosf(w0 * (float)n, &sv, &cv);
            v[c] = make_float2(e * cv, e * sv);
        }
        __syncthreads();
        fft_dif_fwd(v, lds, twp, T1, t);
        // unscramble straight to global (8B scatter, tiny total: 1 MB)
        float2* an = Anat + (size_t)f * L;
        #pragma unroll
        for (int r = 0; r < 16; ++r) an[rev3(16 * t + r)] = v[r];
    } else {
        const int bb = blockIdx.x - F;
        const float* row = x + (size_t)bb * L;
        #pragma unroll
        for (int q = 0; q < 16; ++q) v[q] = make_float2(row[t + 256 * q], 0.0f);
        __syncthreads();
        fft_dif_fwd(v, lds, twp, T1, t);
        // scrambled spectrum, contiguous vectorized store
        float4* o4 = (float4*)(Xs + (size_t)bb * L + 16 * t);
        #pragma unroll
        for (int h = 0; h < 8; ++h)
            o4[h] = make_float4(v[2*h].x, v[2*h].y, v[2*h+1].x, v[2*h+1].y);
    }
}

// ---------------- Kernel 2: Hermitian pairing (F/2 = 16 blocks, ~2 us) -------
// C_j(k) = (G2j(k) + i*G2j1(k))/L, G_f(k) = (conj(Af(k)) + Af(L-k))/2.
// Cs[j][i] = C_j(rev3(i)) so corr can read contiguously.
__global__ void __launch_bounds__(NT) pair_kernel(const float2* __restrict__ Anat,
                                                  float2* __restrict__ Cs) {
    const int j = blockIdx.x;
    const int t = threadIdx.x;
    const float2* a0 = Anat + (size_t)(2 * j) * L;
    const float2* a1 = a0 + L;
    const float sc = 0.5f / (float)L;
    float2* co = Cs + (size_t)j * L;
    #pragma unroll
    for (int c = 0; c < 16; ++c) {
        const int i = t + 256 * c;
        const int k = rev3(i);
        const int km = (L - k) & (L - 1);
        const float2 a0k = a0[k], a0m = a0[km];
        const float2 a1k = a1[k], a1m = a1[km];
        const float g0r = a0k.x + a0m.x, g0i = a0m.y - a0k.y;   // 2*G_{2j}(k)
        const float g1r = a1k.x + a1m.x, g1i = a1m.y - a1k.y;   // 2*G_{2j+1}(k)
        co[i] = make_float2((g0r - g1i) * sc, (g0i + g1r) * sc);
    }
}

// ---------------- Kernel 3: product + inverse DIT FFT (4096 blocks) ----------
// Natural-order real outputs for filters 2jf (Re) and 2jf+1 (Im).
__global__ void __launch_bounds__(NT) corr_kernel(const float2* __restrict__ Xs,
                                                  const float2* __restrict__ Cs,
                                                  float* __restrict__ out) {
    __shared__ float2 lds[L + (L >> 4)];
    __shared__ float2 twp[272];
    __shared__ float2 T1[272];
    const int blk = blockIdx.x;
    const int b = blk >> 4;
    const int jf = blk & 15;
    const int t = threadIdx.x;
    build_tables<1>(twp, T1, t);

    const float2* xr = Xs + (size_t)b * L;
    const float2* cr = Cs + (size_t)jf * L;

    // DIT stage 0 (span 16): product from global, dft16, no twiddle
    float2 v[16];
    const float4* x4 = (const float4*)(xr + 16 * t);
    const float4* c4 = (const float4*)(cr + 16 * t);
    #pragma unroll
    for (int h = 0; h < 8; ++h) {
        const float4 xa = x4[h];
        const float4 ca = c4[h];
        v[2*h]   = cmul(make_float2(xa.x, xa.y), make_float2(ca.x, ca.y));
        v[2*h+1] = cmul(make_float2(xa.z, xa.w), make_float2(ca.z, ca.w));
    }
    dft16<1>(v);
    #pragma unroll
    for (int r = 0; r < 16; ++r) lds[pidx(16 * t + r)] = v[r];
    __syncthreads();
    // DIT stage 1 (span 256): T1-table twiddle, then dft16
    {
        const int base = (t >> 4) * 256 + (t & 15);
        const float2* Tr = T1 + 17 * (t & 15);
        #pragma unroll
        for (int q = 0; q < 16; ++q) v[q] = lds[pidx(base + 16 * q)];
        #pragma unroll
        for (int q = 1; q < 16; ++q) v[q] = cmul(v[q], Tr[q]);
        dft16<1>(v);
        #pragma unroll
        for (int r = 0; r < 16; ++r) lds[pidx(base + 16 * r)] = v[r];
    }
    __syncthreads();
    // DIT stage 2 (span 4096): outputs straight to global, natural order
    {
        #pragma unroll
        for (int q = 0; q < 16; ++q) v[q] = lds[pidx(t + 256 * q)];
        twiddle_pow(v, twp[pidx(t)]);
        dft16<1>(v);
        float* o0 = out + ((size_t)b * F + 2 * jf) * L;
        float* o1 = o0 + L;
        #pragma unroll
        for (int r = 0; r < 16; ++r) {
            __builtin_nontemporal_store(v[r].x, o0 + t + 256 * r);
            __builtin_nontemporal_store(v[r].y, o1 + t + 256 * r);
        }
    }
}

extern "C" void kernel_launch(void* const* d_in, const int* in_sizes, int n_in,
                              void* d_out, int out_size, void* d_ws, size_t ws_size,
                              hipStream_t stream) {
    (void)in_sizes; (void)n_in; (void)out_size; (void)ws_size;
    const float* x  = (const float*)d_in[0];   // [B, L]
    const float* wp = (const float*)d_in[1];   // [F, L]
    const float* fp = (const float*)d_in[2];   // [1, F]
    float* out = (float*)d_out;                // [B, F, L]

    float2* Xs   = (float2*)d_ws;              // B*L complex (scrambled spectra)
    float2* Cs   = Xs + (size_t)B * L;         // (F/2)*L complex (paired filters)
    float2* Anat = Cs + (size_t)(F / 2) * L;   // F*L complex (natural atom spectra)

    prep_kernel<<<dim3(F + B), dim3(NT), 0, stream>>>(x, wp, fp, Xs, Anat);
    pair_kernel<<<dim3(F / 2), dim3(NT), 0, stream>>>(Anat, Cs);
    corr_kernel<<<dim3(B * F / 2), dim3(NT), 0, stream>>>(Xs, Cs, out);
}

// Round 4
// 185.551 us; speedup vs baseline: 1.9736x; 1.0040x over previous
//
#include <hip/hip_runtime.h>
#include <math.h>

#define B 256
#define F 32
#define L 4096
#define NT 256
#define TWO_PI 6.28318530717958647692f

// LDS padding: +1 float2 per 16 -> conflict-free for all FFT stage strides
__device__ __forceinline__ int pidx(int i) { return i + (i >> 4); }

// reverse the 3 base-16 digits of i in [0,4096)
__device__ __forceinline__ int rev3(int i) {
    return ((i & 15) << 8) | (i & 0xF0) | (i >> 8);
}

__device__ __forceinline__ float2 cmul(float2 a, float2 b) {
    return make_float2(a.x * b.x - a.y * b.y, a.x * b.y + a.y * b.x);
}
__device__ __forceinline__ float2 cmulc(float2 a, float cr, float ci) {
    return make_float2(a.x * cr - a.y * ci, a.x * ci + a.y * cr);
}

// radix-4 butterfly, SGN=-1 forward, +1 inverse
template<int SGN>
__device__ __forceinline__ void dft4(float2& a, float2& b, float2& c, float2& d) {
    const float s = (float)SGN;
    float2 t0 = make_float2(a.x + c.x, a.y + c.y);
    float2 t1 = make_float2(a.x - c.x, a.y - c.y);
    float2 t2 = make_float2(b.x + d.x, b.y + d.y);
    float2 t3 = make_float2(b.x - d.x, b.y - d.y);
    float2 it3 = make_float2(-s * t3.y, s * t3.x);   // SGN*i*t3
    a = make_float2(t0.x + t2.x, t0.y + t2.y);
    c = make_float2(t0.x - t2.x, t0.y - t2.y);
    b = make_float2(t1.x + it3.x, t1.y + it3.y);
    d = make_float2(t1.x - it3.x, t1.y - it3.y);
}

// 16-point DFT in registers: v[p] = sum_q v_in[q] * exp(SGN*2pi*i*p*q/16)
template<int SGN>
__device__ __forceinline__ void dft16(float2 v[16]) {
    const float s = (float)SGN;
    const float C1 = 0.92387953251128675613f;   // cos(pi/8)
    const float S1 = 0.38268343236508977173f;   // sin(pi/8)
    const float C2 = 0.70710678118654752440f;   // cos(pi/4)
    #pragma unroll
    for (int c = 0; c < 4; ++c) dft4<SGN>(v[c], v[c + 4], v[c + 8], v[c + 12]);
    v[5]  = cmulc(v[5],  C1,  s * S1);              // W^1
    v[6]  = cmulc(v[6],  C2,  s * C2);              // W^2
    v[7]  = cmulc(v[7],  S1,  s * C1);              // W^3
    v[9]  = cmulc(v[9],  C2,  s * C2);              // W^2
    v[10] = make_float2(-s * v[10].y, s * v[10].x); // W^4 = SGN*i
    v[11] = cmulc(v[11], -C2, s * C2);              // W^6
    v[13] = cmulc(v[13], S1,  s * C1);              // W^3
    v[14] = cmulc(v[14], -C2, s * C2);              // W^6
    v[15] = cmulc(v[15], -C1, -s * S1);             // W^9
    float2 o[16];
    #pragma unroll
    for (int m = 0; m < 4; ++m) {
        float2 a = v[4*m], b = v[4*m+1], c = v[4*m+2], d = v[4*m+3];
        dft4<SGN>(a, b, c, d);
        o[m] = a; o[m+4] = b; o[m+8] = c; o[m+12] = d;
    }
    #pragma unroll
    for (int i = 0; i < 16; ++i) v[i] = o[i];
}

// v[q] *= w1^q for q=1..15 (recursive powers)
__device__ __forceinline__ void twiddle_pow(float2 v[16], float2 w1) {
    float2 w = w1;
    #pragma unroll
    for (int q = 1; q < 16; ++q) {
        v[q] = cmul(v[q], w);
        w = cmul(w, w1);
    }
}

// twp[pidx(t)] = exp(SGN*i*2pi*t/L), t in [0,256)
// T1[17*(t>>4)+(t&15)] = exp(SGN*i*2pi*(t>>4)*(t&15)/256)   (stage-"256" twiddles)
template<int SGN>
__device__ __forceinline__ void build_tables(float2* twp, float2* T1, int t) {
    float sv, cv;
    float a1 = (float)SGN * (TWO_PI / (float)L) * (float)t;
    sincosf(a1, &sv, &cv);
    twp[pidx(t)] = make_float2(cv, sv);
    float a2 = (float)SGN * (TWO_PI / 256.0f) * (float)((t >> 4) * (t & 15));
    sincosf(a2, &sv, &cv);
    T1[17 * (t >> 4) + (t & 15)] = make_float2(cv, sv);
}

// Forward DIF FFT: input v[q] = data[t + 256*q] (natural order).
// Output: v[r] = X(rev3(16*t + r))  (digit-reversed / scrambled).
// Caller must __syncthreads() after build_tables/LDS reuse before calling.
__device__ __forceinline__ void fft_dif_fwd(float2 v[16], float2* lds,
                                            const float2* twp, const float2* T1, int t) {
    // stage A (span 4096)
    dft16<-1>(v);
    twiddle_pow(v, twp[pidx(t)]);
    #pragma unroll
    for (int p = 0; p < 16; ++p) lds[pidx(t + 256 * p)] = v[p];
    __syncthreads();
    // stage B (span 256): twiddles from T1 table
    const int base = (t >> 4) * 256 + (t & 15);
    #pragma unroll
    for (int q = 0; q < 16; ++q) v[q] = lds[pidx(base + 16 * q)];
    dft16<-1>(v);
    {
        const float2* Tr = T1 + 17 * (t & 15);
        #pragma unroll
        for (int p = 1; p < 16; ++p) v[p] = cmul(v[p], Tr[p]);
    }
    #pragma unroll
    for (int p = 0; p < 16; ++p) lds[pidx(base + 16 * p)] = v[p];
    __syncthreads();
    // stage C (span 16)
    #pragma unroll
    for (int q = 0; q < 16; ++q) v[q] = lds[pidx(16 * t + q)];
    dft16<-1>(v);
}

// ---------------- Kernel 1: fused prep (F/2 + B = 272 blocks) ----------------
// Blocks [0,F/2): filter pair (2j,2j+1): softmax+atom+FFT both, then build
//   C_j(k) = (G2j(k)+i*G2j1(k))/L, G_f(k)=(conj(Af(k))+Af(L-k))/2,
//   stored scrambled: Cs[j][i] = C_j(rev3(i)).
// Blocks [F/2,..): forward FFT of x rows -> Xs[b] (scrambled, contiguous).
__global__ void __launch_bounds__(NT) prep_kernel(const float* __restrict__ x,
                                                  const float* __restrict__ wp,
                                                  const float* __restrict__ fp,
                                                  float2* __restrict__ Xs,
                                                  float2* __restrict__ Cs) {
    __shared__ float2 lds[L + (L >> 4)];
    __shared__ float2 twp[272];
    __shared__ float2 T1[272];
    __shared__ float2 bufa[L];
    __shared__ float2 bufb[L];
    __shared__ float red[4];
    const int t = threadIdx.x;
    build_tables<-1>(twp, T1, t);
    float2 v[16];

    if (blockIdx.x < F / 2) {
        const int j = blockIdx.x;
        for (int half = 0; half < 2; ++half) {
            const int f = 2 * j + half;
            const float* row = wp + (size_t)f * L;
            // register-resident softmax (single global pass)
            float rv[16];
            #pragma unroll
            for (int c = 0; c < 16; ++c) rv[c] = row[t + 256 * c];
            float m = -INFINITY;
            #pragma unroll
            for (int c = 0; c < 16; ++c) m = fmaxf(m, rv[c]);
            #pragma unroll
            for (int off = 32; off; off >>= 1) m = fmaxf(m, __shfl_down(m, off));
            if ((t & 63) == 0) red[t >> 6] = m;
            __syncthreads();
            m = fmaxf(fmaxf(red[0], red[1]), fmaxf(red[2], red[3]));
            __syncthreads();
            float s = 0.0f;
            #pragma unroll
            for (int c = 0; c < 16; ++c) { rv[c] = expf(rv[c] - m); s += rv[c]; }
            #pragma unroll
            for (int off = 32; off; off >>= 1) s += __shfl_down(s, off);
            if ((t & 63) == 0) red[t >> 6] = s;
            __syncthreads();
            s = red[0] + red[1] + red[2] + red[3];
            const float inv = 1.0f / s;
            const float fr = 0.5f / (1.0f + expf(-fp[f]));
            const float w0 = -TWO_PI * fr;
            #pragma unroll
            for (int c = 0; c < 16; ++c) {
                const int n = t + 256 * c;
                const float e = rv[c] * inv;
                float sv, cv;
                sincosf(w0 * (float)n, &sv, &cv);
                v[c] = make_float2(e * cv, e * sv);
            }
            __syncthreads();   // lds free (prev half done) + tables/red settled
            fft_dif_fwd(v, lds, twp, T1, t);
            float2* buf = half ? bufb : bufa;
            #pragma unroll
            for (int r = 0; r < 16; ++r) buf[rev3(16 * t + r)] = v[r];
            __syncthreads();
        }
        // pairing + scramble + scale, coalesced global writes
        const float sc = 0.5f / (float)L;
        float2* co = Cs + (size_t)j * L;
        #pragma unroll
        for (int c = 0; c < 16; ++c) {
            const int i = t + 256 * c;
            const int k = rev3(i);
            const int km = (L - k) & (L - 1);
            const float2 a0k = bufa[k], a0m = bufa[km];
            const float2 a1k = bufb[k], a1m = bufb[km];
            const float g0r = a0k.x + a0m.x, g0i = a0m.y - a0k.y;   // 2*G_{2j}(k)
            const float g1r = a1k.x + a1m.x, g1i = a1m.y - a1k.y;   // 2*G_{2j+1}(k)
            co[i] = make_float2((g0r - g1i) * sc, (g0i + g1r) * sc);
        }
    } else {
        const int bb = blockIdx.x - F / 2;
        const float* row = x + (size_t)bb * L;
        #pragma unroll
        for (int q = 0; q < 16; ++q) v[q] = make_float2(row[t + 256 * q], 0.0f);
        __syncthreads();
        fft_dif_fwd(v, lds, twp, T1, t);
        float4* o4 = (float4*)(Xs + (size_t)bb * L + 16 * t);
        #pragma unroll
        for (int h = 0; h < 8; ++h)
            o4[h] = make_float4(v[2*h].x, v[2*h].y, v[2*h+1].x, v[2*h+1].y);
    }
}

// ---------------- Kernel 2: product + inverse DIT FFT (2048 blocks) ----------
// Each block: one x-row b, TWO filter pairs (jf8, jf8+8), Xs held in registers.
// XCD swizzle: blk % 8 == b % 8, so each XCD only reads its own 32 Xs rows
// (1 MB -> resident in that XCD's 4 MiB L2).
__global__ void __launch_bounds__(NT) corr_kernel(const float2* __restrict__ Xs,
                                                  const float2* __restrict__ Cs,
                                                  float* __restrict__ out) {
    __shared__ float2 lds[L + (L >> 4)];
    __shared__ float2 twp[272];
    __shared__ float2 T1[272];
    const int blk = blockIdx.x;          // [0, 2048)
    const int rest = blk >> 3;           // [0, 256)
    const int jf8 = rest & 7;            // [0, 8)
    const int b = ((rest >> 3) << 3) | (blk & 7);
    const int t = threadIdx.x;
    build_tables<1>(twp, T1, t);

    // x spectrum row -> registers, reused for both filter pairs
    float2 xv[16];
    {
        const float4* x4 = (const float4*)(Xs + (size_t)b * L + 16 * t);
        #pragma unroll
        for (int h = 0; h < 8; ++h) {
            const float4 xa = x4[h];
            xv[2*h]   = make_float2(xa.x, xa.y);
            xv[2*h+1] = make_float2(xa.z, xa.w);
        }
    }

    #pragma unroll
    for (int ff = 0; ff < 2; ++ff) {
        const int jf = jf8 + 8 * ff;
        float2 v[16];
        {
            const float4* c4 = (const float4*)(Cs + (size_t)jf * L + 16 * t);
            #pragma unroll
            for (int h = 0; h < 8; ++h) {
                const float4 ca = c4[h];
                v[2*h]   = cmul(xv[2*h],   make_float2(ca.x, ca.y));
                v[2*h+1] = cmul(xv[2*h+1], make_float2(ca.z, ca.w));
            }
        }
        // DIT stage 0 (span 16)
        dft16<1>(v);
        #pragma unroll
        for (int r = 0; r < 16; ++r) lds[pidx(16 * t + r)] = v[r];
        __syncthreads();
        // DIT stage 1 (span 256)
        {
            const int base = (t >> 4) * 256 + (t & 15);
            const float2* Tr = T1 + 17 * (t & 15);
            #pragma unroll
            for (int q = 0; q < 16; ++q) v[q] = lds[pidx(base + 16 * q)];
            #pragma unroll
            for (int q = 1; q < 16; ++q) v[q] = cmul(v[q], Tr[q]);
            dft16<1>(v);
            #pragma unroll
            for (int r = 0; r < 16; ++r) lds[pidx(base + 16 * r)] = v[r];
        }
        __syncthreads();
        // DIT stage 2 (span 4096): outputs straight to global, natural order
        #pragma unroll
        for (int q = 0; q < 16; ++q) v[q] = lds[pidx(t + 256 * q)];
        if (ff == 0) __syncthreads();    // lds consumed; safe to reuse next iter
        twiddle_pow(v, twp[pidx(t)]);
        dft16<1>(v);
        float* o0 = out + ((size_t)b * F + 2 * jf) * L;
        float* o1 = o0 + L;
        #pragma unroll
        for (int r = 0; r < 16; ++r) {
            __builtin_nontemporal_store(v[r].x, o0 + t + 256 * r);
            __builtin_nontemporal_store(v[r].y, o1 + t + 256 * r);
        }
    }
}

extern "C" void kernel_launch(void* const* d_in, const int* in_sizes, int n_in,
                              void* d_out, int out_size, void* d_ws, size_t ws_size,
                              hipStream_t stream) {
    (void)in_sizes; (void)n_in; (void)out_size; (void)ws_size;
    const float* x  = (const float*)d_in[0];   // [B, L]
    const float* wp = (const float*)d_in[1];   // [F, L]
    const float* fp = (const float*)d_in[2];   // [1, F]
    float* out = (float*)d_out;                // [B, F, L]

    float2* Xs = (float2*)d_ws;                // B*L complex (scrambled spectra)
    float2* Cs = Xs + (size_t)B * L;           // (F/2)*L complex (paired filters)

    prep_kernel<<<dim3(F / 2 + B), dim3(NT), 0, stream>>>(x, wp, fp, Xs, Cs);
    corr_kernel<<<dim3(B * F / 4), dim3(NT), 0, stream>>>(Xs, Cs, out);
}

// Round 5
// 181.798 us; speedup vs baseline: 2.0143x; 1.0206x over previous
//
#include <hip/hip_runtime.h>
#include <math.h>

#define B 256
#define F 32
#define L 4096
#define NT 256
#define TWO_PI 6.28318530717958647692f

// LDS padding: +1 float2 per 16 -> conflict-free for strides 1/16/256 (measured 0 conflicts)
__device__ __forceinline__ int pidx(int i) { return i + (i >> 4); }

// reverse the 3 base-16 digits of i in [0,4096)
__device__ __forceinline__ int rev3(int i) {
    return ((i & 15) << 8) | (i & 0xF0) | (i >> 8);
}

__device__ __forceinline__ float2 cmul(float2 a, float2 b) {
    return make_float2(a.x * b.x - a.y * b.y, a.x * b.y + a.y * b.x);
}
__device__ __forceinline__ float2 cmulc(float2 a, float cr, float ci) {
    return make_float2(a.x * cr - a.y * ci, a.x * ci + a.y * cr);
}

// radix-4 butterfly, SGN=-1 forward, +1 inverse
template<int SGN>
__device__ __forceinline__ void dft4(float2& a, float2& b, float2& c, float2& d) {
    const float s = (float)SGN;
    float2 t0 = make_float2(a.x + c.x, a.y + c.y);
    float2 t1 = make_float2(a.x - c.x, a.y - c.y);
    float2 t2 = make_float2(b.x + d.x, b.y + d.y);
    float2 t3 = make_float2(b.x - d.x, b.y - d.y);
    float2 it3 = make_float2(-s * t3.y, s * t3.x);   // SGN*i*t3
    a = make_float2(t0.x + t2.x, t0.y + t2.y);
    c = make_float2(t0.x - t2.x, t0.y - t2.y);
    b = make_float2(t1.x + it3.x, t1.y + it3.y);
    d = make_float2(t1.x - it3.x, t1.y - it3.y);
}

// 16-point DFT in registers: v[p] = sum_q v_in[q] * exp(SGN*2pi*i*p*q/16)
template<int SGN>
__device__ __forceinline__ void dft16(float2 v[16]) {
    const float s = (float)SGN;
    const float C1 = 0.92387953251128675613f;   // cos(pi/8)
    const float S1 = 0.38268343236508977173f;   // sin(pi/8)
    const float C2 = 0.70710678118654752440f;   // cos(pi/4)
    #pragma unroll
    for (int c = 0; c < 4; ++c) dft4<SGN>(v[c], v[c + 4], v[c + 8], v[c + 12]);
    v[5]  = cmulc(v[5],  C1,  s * S1);              // W^1
    v[6]  = cmulc(v[6],  C2,  s * C2);              // W^2
    v[7]  = cmulc(v[7],  S1,  s * C1);              // W^3
    v[9]  = cmulc(v[9],  C2,  s * C2);              // W^2
    v[10] = make_float2(-s * v[10].y, s * v[10].x); // W^4 = SGN*i
    v[11] = cmulc(v[11], -C2, s * C2);              // W^6
    v[13] = cmulc(v[13], S1,  s * C1);              // W^3
    v[14] = cmulc(v[14], -C2, s * C2);              // W^6
    v[15] = cmulc(v[15], -C1, -s * S1);             // W^9
    float2 o[16];
    #pragma unroll
    for (int m = 0; m < 4; ++m) {
        float2 a = v[4*m], b = v[4*m+1], c = v[4*m+2], d = v[4*m+3];
        dft4<SGN>(a, b, c, d);
        o[m] = a; o[m+4] = b; o[m+8] = c; o[m+12] = d;
    }
    #pragma unroll
    for (int i = 0; i < 16; ++i) v[i] = o[i];
}

// v[q] *= w1^q for q=1..15 (recursive powers)
__device__ __forceinline__ void twiddle_pow(float2 v[16], float2 w1) {
    float2 w = w1;
    #pragma unroll
    for (int q = 1; q < 16; ++q) {
        v[q] = cmul(v[q], w);
        w = cmul(w, w1);
    }
}

// twp[pidx(t)] = exp(SGN*i*2pi*t/L), t in [0,256)
// T1[17*(t>>4)+(t&15)] = exp(SGN*i*2pi*(t>>4)*(t&15)/256)
template<int SGN>
__device__ __forceinline__ void build_tables(float2* twp, float2* T1, int t) {
    float sv, cv;
    float a1 = (float)SGN * (TWO_PI / (float)L) * (float)t;
    sincosf(a1, &sv, &cv);
    twp[pidx(t)] = make_float2(cv, sv);
    float a2 = (float)SGN * (TWO_PI / 256.0f) * (float)((t >> 4) * (t & 15));
    sincosf(a2, &sv, &cv);
    T1[17 * (t >> 4) + (t & 15)] = make_float2(cv, sv);
}

// Forward DIF FFT: input v[q] = data[t + 256*q] (natural order).
// Output: v[r] = X(rev3(16*t + r))  (digit-reversed / scrambled).
__device__ __forceinline__ void fft_dif_fwd(float2 v[16], float2* lds,
                                            const float2* twp, const float2* T1, int t) {
    dft16<-1>(v);
    twiddle_pow(v, twp[pidx(t)]);
    #pragma unroll
    for (int p = 0; p < 16; ++p) lds[pidx(t + 256 * p)] = v[p];
    __syncthreads();
    const int base = (t >> 4) * 256 + (t & 15);
    #pragma unroll
    for (int q = 0; q < 16; ++q) v[q] = lds[pidx(base + 16 * q)];
    dft16<-1>(v);
    {
        const float2* Tr = T1 + 17 * (t & 15);
        #pragma unroll
        for (int p = 1; p < 16; ++p) v[p] = cmul(v[p], Tr[p]);
    }
    #pragma unroll
    for (int p = 0; p < 16; ++p) lds[pidx(base + 16 * p)] = v[p];
    __syncthreads();
    #pragma unroll
    for (int q = 0; q < 16; ++q) v[q] = lds[pidx(16 * t + q)];
    dft16<-1>(v);
}

// ---------------- Kernel 1: fused prep (F + B = 288 blocks) ------------------
// Blocks [0,F): per-filter softmax + atom + forward FFT -> Anat[f] (natural).
// Blocks [F,..): forward FFT of x rows -> Xs[b] (scrambled, contiguous).
__global__ void __launch_bounds__(NT) prep_kernel(const float* __restrict__ x,
                                                  const float* __restrict__ wp,
                                                  const float* __restrict__ fp,
                                                  float2* __restrict__ Xs,
                                                  float2* __restrict__ Anat) {
    __shared__ float2 lds[L + (L >> 4)];
    __shared__ float2 twp[272];
    __shared__ float2 T1[272];
    __shared__ float red[4];
    const int t = threadIdx.x;
    build_tables<-1>(twp, T1, t);
    float2 v[16];

    if (blockIdx.x < F) {
        const int f = blockIdx.x;
        const float* row = wp + (size_t)f * L;
        float rv[16];
        #pragma unroll
        for (int c = 0; c < 16; ++c) rv[c] = row[t + 256 * c];
        float m = -INFINITY;
        #pragma unroll
        for (int c = 0; c < 16; ++c) m = fmaxf(m, rv[c]);
        #pragma unroll
        for (int off = 32; off; off >>= 1) m = fmaxf(m, __shfl_down(m, off));
        if ((t & 63) == 0) red[t >> 6] = m;
        __syncthreads();
        m = fmaxf(fmaxf(red[0], red[1]), fmaxf(red[2], red[3]));
        __syncthreads();
        float s = 0.0f;
        #pragma unroll
        for (int c = 0; c < 16; ++c) { rv[c] = expf(rv[c] - m); s += rv[c]; }
        #pragma unroll
        for (int off = 32; off; off >>= 1) s += __shfl_down(s, off);
        if ((t & 63) == 0) red[t >> 6] = s;
        __syncthreads();
        s = red[0] + red[1] + red[2] + red[3];
        const float inv = 1.0f / s;
        const float fr = 0.5f / (1.0f + expf(-fp[f]));
        const float w0 = -TWO_PI * fr;
        #pragma unroll
        for (int c = 0; c < 16; ++c) {
            const int n = t + 256 * c;
            const float e = rv[c] * inv;
            float sv, cv;
            sincosf(w0 * (float)n, &sv, &cv);
            v[c] = make_float2(e * cv, e * sv);
        }
        __syncthreads();
        fft_dif_fwd(v, lds, twp, T1, t);
        float2* an = Anat + (size_t)f * L;
        #pragma unroll
        for (int r = 0; r < 16; ++r) an[rev3(16 * t + r)] = v[r];
    } else {
        const int bb = blockIdx.x - F;
        const float* row = x + (size_t)bb * L;
        #pragma unroll
        for (int q = 0; q < 16; ++q) v[q] = make_float2(row[t + 256 * q], 0.0f);
        __syncthreads();
        fft_dif_fwd(v, lds, twp, T1, t);
        float4* o4 = (float4*)(Xs + (size_t)bb * L + 16 * t);
        #pragma unroll
        for (int h = 0; h < 8; ++h)
            o4[h] = make_float4(v[2*h].x, v[2*h].y, v[2*h+1].x, v[2*h+1].y);
    }
}

// ---------------- Kernel 2: Hermitian pairing (F/2 = 16 blocks, ~2 us) -------
// C_j(k) = (G2j(k) + i*G2j1(k))/L, G_f(k) = (conj(Af(k)) + Af(L-k))/2.
// Cs[j][i] = C_j(rev3(i)) so corr can read contiguously.
__global__ void __launch_bounds__(NT) pair_kernel(const float2* __restrict__ Anat,
                                                  float2* __restrict__ Cs) {
    const int j = blockIdx.x;
    const int t = threadIdx.x;
    const float2* a0 = Anat + (size_t)(2 * j) * L;
    const float2* a1 = a0 + L;
    const float sc = 0.5f / (float)L;
    float2* co = Cs + (size_t)j * L;
    #pragma unroll
    for (int c = 0; c < 16; ++c) {
        const int i = t + 256 * c;
        const int k = rev3(i);
        const int km = (L - k) & (L - 1);
        const float2 a0k = a0[k], a0m = a0[km];
        const float2 a1k = a1[k], a1m = a1[km];
        const float g0r = a0k.x + a0m.x, g0i = a0m.y - a0k.y;   // 2*G_{2j}(k)
        const float g1r = a1k.x + a1m.x, g1i = a1m.y - a1k.y;   // 2*G_{2j+1}(k)
        co[i] = make_float2((g0r - g1i) * sc, (g0i + g1r) * sc);
    }
}

// ---------------- Kernel 3: product + inverse DIT FFT (4096 blocks) ----------
// One FFT per block; stores only at block end (no barrier-after-store drain).
// __launch_bounds__(256,4): cap VGPR<=128 so LDS (39.2 KB) is the binding
// limit -> 4 blocks/CU, 4096 blocks = exactly 4 full rounds.
// XCD swizzle: blk%8 == b%8 so each XCD's Xs working set is 32 rows (1 MB, L2-resident).
__global__ void __launch_bounds__(NT, 4) corr_kernel(const float2* __restrict__ Xs,
                                                     const float2* __restrict__ Cs,
                                                     float* __restrict__ out) {
    __shared__ float2 lds[L + (L >> 4)];
    __shared__ float2 twp[272];
    __shared__ float2 T1[272];
    const int blk = blockIdx.x;                    // [0, 4096)
    const int jf = (blk >> 3) & 15;                // filter pair
    const int b = ((blk >> 7) << 3) | (blk & 7);   // x row, blk%8 == b%8
    const int t = threadIdx.x;

    // issue global loads first so they overlap the sincosf table build
    const float4* x4 = (const float4*)(Xs + (size_t)b * L + 16 * t);
    const float4* c4 = (const float4*)(Cs + (size_t)jf * L + 16 * t);
    float4 xa[8], ca[8];
    #pragma unroll
    for (int h = 0; h < 8; ++h) { xa[h] = x4[h]; ca[h] = c4[h]; }

    build_tables<1>(twp, T1, t);

    // DIT stage 0 (span 16): product, dft16, no twiddle
    float2 v[16];
    #pragma unroll
    for (int h = 0; h < 8; ++h) {
        v[2*h]   = cmul(make_float2(xa[h].x, xa[h].y), make_float2(ca[h].x, ca[h].y));
        v[2*h+1] = cmul(make_float2(xa[h].z, xa[h].w), make_float2(ca[h].z, ca[h].w));
    }
    dft16<1>(v);
    #pragma unroll
    for (int r = 0; r < 16; ++r) lds[pidx(16 * t + r)] = v[r];
    __syncthreads();
    // DIT stage 1 (span 256)
    {
        const int base = (t >> 4) * 256 + (t & 15);
        const float2* Tr = T1 + 17 * (t & 15);
        #pragma unroll
        for (int q = 0; q < 16; ++q) v[q] = lds[pidx(base + 16 * q)];
        #pragma unroll
        for (int q = 1; q < 16; ++q) v[q] = cmul(v[q], Tr[q]);
        dft16<1>(v);
        #pragma unroll
        for (int r = 0; r < 16; ++r) lds[pidx(base + 16 * r)] = v[r];
    }
    __syncthreads();
    // DIT stage 2 (span 4096): outputs straight to global, natural order
    #pragma unroll
    for (int q = 0; q < 16; ++q) v[q] = lds[pidx(t + 256 * q)];
    twiddle_pow(v, twp[pidx(t)]);
    dft16<1>(v);
    float* o0 = out + ((size_t)b * F + 2 * jf) * L;
    float* o1 = o0 + L;
    #pragma unroll
    for (int r = 0; r < 16; ++r) {
        __builtin_nontemporal_store(v[r].x, o0 + t + 256 * r);
        __builtin_nontemporal_store(v[r].y, o1 + t + 256 * r);
    }
}

extern "C" void kernel_launch(void* const* d_in, const int* in_sizes, int n_in,
                              void* d_out, int out_size, void* d_ws, size_t ws_size,
                              hipStream_t stream) {
    (void)in_sizes; (void)n_in; (void)out_size; (void)ws_size;
    const float* x  = (const float*)d_in[0];   // [B, L]
    const float* wp = (const float*)d_in[1];   // [F, L]
    const float* fp = (const float*)d_in[2];   // [1, F]
    float* out = (float*)d_out;                // [B, F, L]

    float2* Xs   = (float2*)d_ws;              // B*L complex (scrambled spectra)
    float2* Cs   = Xs + (size_t)B * L;         // (F/2)*L complex (paired filters)
    float2* Anat = Cs + (size_t)(F / 2) * L;   // F*L complex (natural atom spectra)

    prep_kernel<<<dim3(F + B), dim3(NT), 0, stream>>>(x, wp, fp, Xs, Anat);
    pair_kernel<<<dim3(F / 2), dim3(NT), 0, stream>>>(Anat, Cs);
    corr_kernel<<<dim3(B * F / 2), dim3(NT), 0, stream>>>(Xs, Cs, out);
}